// Round 7
// baseline (1053.147 us; speedup 1.0000x reference)
//
#include <hip/hip_runtime.h>

typedef unsigned short UST;
typedef __attribute__((ext_vector_type(8))) __bf16 bf16x8;
typedef __attribute__((ext_vector_type(4))) float f32x4;

__device__ __forceinline__ float bf2f(UST u) {
    union { unsigned int i; float f; } v; v.i = ((unsigned int)u) << 16; return v.f;
}
__device__ __forceinline__ UST f2bf(float f) {
    union { float f; unsigned int i; } v; v.f = f;
    return (UST)((v.i + 0x7fffu + ((v.i >> 16) & 1u)) >> 16);
}

__device__ __forceinline__ void gl2lds16(const UST* g, UST* l) {
    __builtin_amdgcn_global_load_lds(
        (const __attribute__((address_space(1))) unsigned int*)g,
        (__attribute__((address_space(3))) unsigned int*)l, 16, 0, 0);
}

#define WB4 asm volatile("s_waitcnt vmcnt(4)\n\ts_barrier" ::: "memory")
#define WB0 asm volatile("s_waitcnt vmcnt(0)\n\ts_barrier" ::: "memory")
#define LGB asm volatile("s_waitcnt lgkmcnt(0)\n\ts_barrier" ::: "memory")

// ---------------------------------------------------------------------------
// Weight prep v3 (unchanged): W'[o,i] = (qw/15*2-1)*scale + (lb@la)[o,i].
// ---------------------------------------------------------------------------
__global__ __launch_bounds__(256) void prep_w(
    const int* __restrict__ qw, const float* __restrict__ scale,
    const float* __restrict__ la, const float* __restrict__ lb,
    UST* __restrict__ wp)
{
    int l = blockIdx.x, ot = blockIdx.y, it = blockIdx.z;   // 18 x 8 x 8
    __shared__ float buf[8192];
    __shared__ float sc_s[128 * 8];
    int t = threadIdx.x;
    int wave = t >> 6, lane = t & 63;
    int wm = wave >> 1, wn = wave & 1;
    int la15 = lane & 15, qa = lane >> 4;

    {
        int e = t * 4;
        int o = e >> 3, g = e & 7;
        const float* sb = scale + ((size_t)l * 1024 + ot * 128 + o) * 64 + it * 8 + g;
        *(float4*)&sc_s[e] = *(const float4*)sb;
    }

    float* last = buf;
    {
        const float* laB = la + (size_t)l * 32 * 1024 + it * 128;
        #pragma unroll
        for (int p = 0; p < 4; p++) {
            int e = t * 4 + p * 1024;
            int r = e >> 7, i0 = e & 127;
            float4 v = *(const float4*)(laB + (size_t)r * 1024 + i0);
            last[(i0 + 0) * 33 + r] = v.x;
            last[(i0 + 1) * 33 + r] = v.y;
            last[(i0 + 2) * 33 + r] = v.z;
            last[(i0 + 3) * 33 + r] = v.w;
        }
    }

    bf16x8 af[4];
    const float* lbL = lb + ((size_t)l * 1024 + ot * 128 + wm * 64 + la15) * 32 + qa * 8;
    #pragma unroll
    for (int mi = 0; mi < 4; mi++) {
        float4 u0 = *(const float4*)(lbL + mi * 16 * 32);
        float4 u1 = *(const float4*)(lbL + mi * 16 * 32 + 4);
        union { bf16x8 v; UST u[8]; } A;
        A.u[0] = f2bf(u0.x); A.u[1] = f2bf(u0.y); A.u[2] = f2bf(u0.z); A.u[3] = f2bf(u0.w);
        A.u[4] = f2bf(u1.x); A.u[5] = f2bf(u1.y); A.u[6] = f2bf(u1.z); A.u[7] = f2bf(u1.w);
        af[mi] = A.v;
    }

    __syncthreads();

    bf16x8 bfr[4];
    #pragma unroll
    for (int ni = 0; ni < 4; ni++) {
        int iloc = wn * 64 + ni * 16 + la15;
        const float* pp = &last[iloc * 33 + qa * 8];
        union { bf16x8 v; UST u[8]; } B;
        #pragma unroll
        for (int j = 0; j < 8; j++) B.u[j] = f2bf(pp[j]);
        bfr[ni] = B.v;
    }

    f32x4 acc[4][4];
    #pragma unroll
    for (int mi = 0; mi < 4; mi++)
        #pragma unroll
        for (int ni = 0; ni < 4; ni++) {
            acc[mi][ni] = (f32x4){0.f, 0.f, 0.f, 0.f};
            acc[mi][ni] = __builtin_amdgcn_mfma_f32_16x16x32_bf16(
                af[mi], bfr[ni], acc[mi][ni], 0, 0, 0);
        }

    __syncthreads();

    float* cs = buf;
    int cc = t & 15, rw = t >> 4;
    UST* wL = wp + (size_t)l * 1048576;
    const int* qL = qw + (size_t)l * 1048576;
    #pragma unroll
    for (int h = 0; h < 2; ++h) {
        int4 qd[4][2];
        #pragma unroll
        for (int g = 0; g < 4; g++) {
            int rl = g * 16 + rw;
            const int* qrow = qL + (size_t)(ot * 128 + h * 64 + rl) * 1024
                              + it * 128 + cc * 8;
            qd[g][0] = *(const int4*)qrow;
            qd[g][1] = *(const int4*)(qrow + 4);
        }
        if (wm == h) {
            #pragma unroll
            for (int mi = 0; mi < 4; mi++)
                #pragma unroll
                for (int ni = 0; ni < 4; ni++) {
                    int colx = (wn * 64 + ni * 16 + la15) ^ (qa << 4);
                    #pragma unroll
                    for (int r2 = 0; r2 < 4; r2++) {
                        int rl = mi * 16 + qa * 4 + r2;
                        cs[rl * 128 + colx] = acc[mi][ni][r2];
                    }
                }
        }
        LGB;
        #pragma unroll
        for (int g = 0; g < 4; ++g) {
            int rl = g * 16 + rw;
            int swz = ((rl >> 2) & 3) << 2;
            int gr0 = ((cc * 2) ^ swz) * 4;
            float4 v0 = *(const float4*)&cs[rl * 128 + gr0];
            float4 v1 = *(const float4*)&cs[rl * 128 + gr0 + 4];
            float s = sc_s[(h * 64 + rl) * 8 + (cc >> 1)];
            float t2 = s * (2.0f / 15.0f);
            float o0 = fmaf((float)qd[g][0].x, t2, v0.x - s);
            float o1 = fmaf((float)qd[g][0].y, t2, v0.y - s);
            float o2 = fmaf((float)qd[g][0].z, t2, v0.z - s);
            float o3 = fmaf((float)qd[g][0].w, t2, v0.w - s);
            float o4 = fmaf((float)qd[g][1].x, t2, v1.x - s);
            float o5 = fmaf((float)qd[g][1].y, t2, v1.y - s);
            float o6 = fmaf((float)qd[g][1].z, t2, v1.z - s);
            float o7 = fmaf((float)qd[g][1].w, t2, v1.w - s);
            uint4 pk;
            pk.x = (unsigned)f2bf(o0) | ((unsigned)f2bf(o1) << 16);
            pk.y = (unsigned)f2bf(o2) | ((unsigned)f2bf(o3) << 16);
            pk.z = (unsigned)f2bf(o4) | ((unsigned)f2bf(o5) << 16);
            pk.w = (unsigned)f2bf(o6) | ((unsigned)f2bf(o7) << 16);
            *(uint4*)&wL[(size_t)(ot * 128 + h * 64 + rl) * 1024 + it * 128 + cc * 8] = pk;
        }
        LGB;
    }
}

__global__ __launch_bounds__(256) void f32_to_bf16(const float* __restrict__ x,
                                                   UST* __restrict__ o)
{
    size_t i = ((size_t)blockIdx.x * 256 + threadIdx.x) * 4;
    float4 v = *(const float4*)(x + i);
    *(ushort4*)(o + i) = make_ushort4(f2bf(v.x), f2bf(v.y), f2bf(v.z), f2bf(v.w));
}

// ---------------------------------------------------------------------------
// GEMM v8: the m97-table winner -- 128x128 tile, 4 waves (2x2), BK=32,
// 2-stage 32KB LDS -> 4 blocks/CU resident (1024 blocks, 16 waves/CU).
// Mechanism (m114/m97): one block's barrier/waitcnt convoy hides under
// the other 3 blocks' MFMA+LDS work -- TLP, not intra-block scheduling.
// All prior rounds ran 1-2 blocks/CU; CU idled at every convoy point.
// Loop skeleton = round-1's verified counted-vmcnt 2-stage.
// ---------------------------------------------------------------------------
#define BK 32

__global__ __launch_bounds__(256, 4) void gemm_ep(
    const UST* __restrict__ X, const UST* __restrict__ W,
    const float* __restrict__ bias,
    UST* __restrict__ outb, const UST* __restrict__ resid,
    float* __restrict__ outf, int mode)
{
    const int K = 1024;
    __shared__ UST smem[16384];   // 2 stages x (A 4096 + B 4096 UST) = 32 KB
    int tid = threadIdx.x;
    int wave = tid >> 6, lane = tid & 63;
    int wm = wave >> 1, wn = wave & 1;         // 2 x 2 waves
    int la15 = lane & 15, qa = lane >> 4;

    int bid = blockIdx.x;
    int xcd = bid & 7, idx = bid >> 3;         // 1024 blocks
    int bm = xcd * 16 + (idx & 15);            // 0..127 (X rows XCD-local)
    int bn = idx >> 4;                         // 0..7

    // staging: per stage per operand 512 chunks of 16B; 2 per thread each
    int c0 = tid, c1 = tid + 256;
    int r0 = c0 >> 2, k0c = ((c0 & 3) ^ ((r0 >> 1) & 3)) * 8;
    int r1 = c1 >> 2, k1c = ((c1 & 3) ^ ((r1 >> 1) & 3)) * 8;
    const UST* gA0 = X + (size_t)(bm * 128 + r0) * K + k0c;
    const UST* gA1 = X + (size_t)(bm * 128 + r1) * K + k1c;
    const UST* gB0 = W + (size_t)(bn * 128 + r0) * K + k0c;
    const UST* gB1 = W + (size_t)(bn * 128 + r1) * K + k1c;

    int offA[4], offB[4];
    #pragma unroll
    for (int i = 0; i < 4; i++) {
        int ra = wm * 64 + i * 16 + la15;
        offA[i] = ra * 32 + ((qa ^ ((ra >> 1) & 3)) * 8);
        int rb = wn * 64 + i * 16 + la15;
        offB[i] = rb * 32 + ((qa ^ ((rb >> 1) & 3)) * 8);
    }

    f32x4 acc[4][4];
    #pragma unroll
    for (int i = 0; i < 4; i++)
        #pragma unroll
        for (int j = 0; j < 4; j++) acc[i][j] = (f32x4){0.f, 0.f, 0.f, 0.f};

    auto issue = [&](int kk, int buf) {
        UST* dA = smem + buf * 8192;
        UST* dB = dA + 4096;
        gl2lds16(gA0 + kk, dA + c0 * 8);
        gl2lds16(gA1 + kk, dA + c1 * 8);
        gl2lds16(gB0 + kk, dB + c0 * 8);
        gl2lds16(gB1 + kk, dB + c1 * 8);
    };
    auto compute = [&](int buf) {
        const UST* pA = smem + buf * 8192;
        const UST* pB = pA + 4096;
        bf16x8 af[4], bfr[4];
        #pragma unroll
        for (int mi = 0; mi < 4; mi++) af[mi] = *(const bf16x8*)&pA[offA[mi]];
        #pragma unroll
        for (int ni = 0; ni < 4; ni++) bfr[ni] = *(const bf16x8*)&pB[offB[ni]];
        __builtin_amdgcn_s_setprio(1);
        #pragma unroll
        for (int mi = 0; mi < 4; mi++)
            #pragma unroll
            for (int ni = 0; ni < 4; ni++)
                acc[mi][ni] = __builtin_amdgcn_mfma_f32_16x16x32_bf16(
                    af[mi], bfr[ni], acc[mi][ni], 0, 0, 0);
        __builtin_amdgcn_s_setprio(0);
    };

    issue(0, 0);
    #pragma unroll 2
    for (int it = 0; it < 31; ++it) {
        int cur = it & 1;
        issue((it + 1) * BK, cur ^ 1);
        WB4;                     // 4 new loads stay in flight; stage it landed
        compute(cur);
        LGB;                     // reads drained before next overwrite
    }
    WB0;
    compute(1);
    LGB;

    // -------- epilogue: 2 strips of 64x128 fp32 (32 KB), coalesced out -----
    // (identical geometry to prep_w's verified epilogue)
    float* cs = (float*)smem;
    int cc = tid & 15, rw = tid >> 4;
    int gcolb = bn * 128 + cc * 8;
    float4 bv0 = *(const float4*)&bias[gcolb];
    float4 bv1 = *(const float4*)&bias[gcolb + 4];

    #pragma unroll
    for (int h = 0; h < 2; ++h) {
        if (wm == h) {
            #pragma unroll
            for (int mi = 0; mi < 4; mi++)
                #pragma unroll
                for (int ni = 0; ni < 4; ni++) {
                    int colx = (wn * 64 + ni * 16 + la15) ^ (qa << 4);
                    #pragma unroll
                    for (int r2 = 0; r2 < 4; r2++) {
                        int rl = mi * 16 + qa * 4 + r2;
                        cs[rl * 128 + colx] = acc[mi][ni][r2];
                    }
                }
        }
        LGB;
        #pragma unroll
        for (int g = 0; g < 4; ++g) {
            int rl = g * 16 + rw;
            int swz = ((rl >> 2) & 3) << 2;
            int gr0 = ((cc * 2) ^ swz) * 4;
            float4 v0 = *(const float4*)&cs[rl * 128 + gr0];
            float4 v1 = *(const float4*)&cs[rl * 128 + gr0 + 4];
            float o0 = v0.x + bv0.x, o1 = v0.y + bv0.y;
            float o2 = v0.z + bv0.z, o3 = v0.w + bv0.w;
            float o4 = v1.x + bv1.x, o5 = v1.y + bv1.y;
            float o6 = v1.z + bv1.z, o7 = v1.w + bv1.w;
            if (mode == 0) {
                o0 = fmaxf(o0, 0.f); o1 = fmaxf(o1, 0.f);
                o2 = fmaxf(o2, 0.f); o3 = fmaxf(o3, 0.f);
                o4 = fmaxf(o4, 0.f); o5 = fmaxf(o5, 0.f);
                o6 = fmaxf(o6, 0.f); o7 = fmaxf(o7, 0.f);
            }
            int grow = bm * 128 + h * 64 + rl;
            size_t base = (size_t)grow * 1024 + gcolb;
            if (mode != 0) {           // residual add (modes 1 and 2)
                ushort4 rv0 = *(const ushort4*)&resid[base];
                ushort4 rv1 = *(const ushort4*)&resid[base + 4];
                o0 += bf2f(rv0.x); o1 += bf2f(rv0.y);
                o2 += bf2f(rv0.z); o3 += bf2f(rv0.w);
                o4 += bf2f(rv1.x); o5 += bf2f(rv1.y);
                o6 += bf2f(rv1.z); o7 += bf2f(rv1.w);
            }
            if (mode == 2) {
                *(float4*)&outf[base] = make_float4(o0, o1, o2, o3);
                *(float4*)&outf[base + 4] = make_float4(o4, o5, o6, o7);
            } else {
                uint4 pk;
                pk.x = (unsigned)f2bf(o0) | ((unsigned)f2bf(o1) << 16);
                pk.y = (unsigned)f2bf(o2) | ((unsigned)f2bf(o3) << 16);
                pk.z = (unsigned)f2bf(o4) | ((unsigned)f2bf(o5) << 16);
                pk.w = (unsigned)f2bf(o6) | ((unsigned)f2bf(o7) << 16);
                *(uint4*)&outb[base] = pk;
            }
        }
        LGB;
    }
}

// ---------------------------------------------------------------------------
// Slim LayerNorm (unchanged).
// ---------------------------------------------------------------------------
__global__ __launch_bounds__(256) void ln_only(
    const UST* __restrict__ s, UST* __restrict__ r,
    const float* __restrict__ g, const float* __restrict__ b)
{
    int wave = threadIdx.x >> 6, lane = threadIdx.x & 63;
    int row = blockIdx.x * 4 + wave;
    const UST* sp = s + (size_t)row * 1024;
    UST* rp = r + (size_t)row * 1024;

    float v[16];
    float sum = 0.f, ss = 0.f;
    #pragma unroll
    for (int k = 0; k < 4; k++) {
        ushort4 hv = *(const ushort4*)(sp + k * 256 + lane * 4);
        float a0 = bf2f(hv.x), a1 = bf2f(hv.y), a2 = bf2f(hv.z), a3 = bf2f(hv.w);
        v[k * 4 + 0] = a0; v[k * 4 + 1] = a1; v[k * 4 + 2] = a2; v[k * 4 + 3] = a3;
        sum += a0 + a1 + a2 + a3;
        ss += a0 * a0 + a1 * a1 + a2 * a2 + a3 * a3;
    }
    #pragma unroll
    for (int off = 32; off > 0; off >>= 1) {
        sum += __shfl_down(sum, off, 64);
        ss  += __shfl_down(ss, off, 64);
    }
    sum = __shfl(sum, 0, 64);
    ss  = __shfl(ss, 0, 64);
    float mean = sum * (1.0f / 1024.0f);
    float var = ss * (1.0f / 1024.0f) - mean * mean;
    float rstd = rsqrtf(var + 1e-5f);

    #pragma unroll
    for (int k = 0; k < 4; k++) {
        int c = k * 256 + lane * 4;
        float4 gv = *(const float4*)(g + c);
        float4 bv = *(const float4*)(b + c);
        ushort4 o;
        o.x = f2bf((v[k * 4 + 0] - mean) * rstd * gv.x + bv.x);
        o.y = f2bf((v[k * 4 + 1] - mean) * rstd * gv.y + bv.y);
        o.z = f2bf((v[k * 4 + 2] - mean) * rstd * gv.z + bv.z);
        o.w = f2bf((v[k * 4 + 3] - mean) * rstd * gv.w + bv.w);
        *(ushort4*)(rp + c) = o;
    }
}

// ---------------------------------------------------------------------------
extern "C" void kernel_launch(void* const* d_in, const int* in_sizes, int n_in,
                              void* d_out, int out_size, void* d_ws, size_t ws_size,
                              hipStream_t stream) {
    const float* x     = (const float*)d_in[0];
    const float* scale = (const float*)d_in[1];
    const float* bias  = (const float*)d_in[2];
    const float* la    = (const float*)d_in[3];
    const float* lb    = (const float*)d_in[4];
    const float* ln_w  = (const float*)d_in[5];
    const float* ln_b  = (const float*)d_in[6];
    const int*   qw    = (const int*)d_in[7];

    const int M = in_sizes[0] / 1024;                  // 16384
    const size_t WPB = (size_t)18 * 1024 * 1024 * 2;
    const size_t ACT = (size_t)M * 1024 * 2;

    UST* wp = (UST*)d_ws;
    UST* A  = (UST*)((char*)d_ws + WPB);            // residual
    UST* Cb = (UST*)((char*)d_ws + WPB + ACT);      // ping
    UST* Bb = (UST*)d_out;                          // pong (dead before fp32 write)

    prep_w<<<dim3(18, 8, 8), 256, 0, stream>>>(qw, scale, la, lb, wp);
    f32_to_bf16<<<(M * 1024) / (256 * 4), 256, 0, stream>>>(x, A);

    int nblk = (M / 128) * 8;                          // 1024 blocks = 4/CU
    int li = 0;
    for (int blk = 0; blk < 6; ++blk) {
        gemm_ep<<<nblk, 256, 0, stream>>>(
            A, wp + (size_t)li * 1024 * 1024, bias + li * 1024, Bb, nullptr, nullptr, 0);
        li++;
        gemm_ep<<<nblk, 256, 0, stream>>>(
            Bb, wp + (size_t)li * 1024 * 1024, bias + li * 1024, Cb, nullptr, nullptr, 0);
        li++;
        if (blk < 5) {
            gemm_ep<<<nblk, 256, 0, stream>>>(
                Cb, wp + (size_t)li * 1024 * 1024, bias + li * 1024, Bb, A, nullptr, 1);
            li++;
            ln_only<<<M / 4, 256, 0, stream>>>(Bb, A, ln_w + blk * 1024, ln_b + blk * 1024);
        } else {
            gemm_ep<<<nblk, 256, 0, stream>>>(
                Cb, wp + (size_t)li * 1024 * 1024, bias + li * 1024, nullptr, A,
                (float*)d_out, 2);
            li++;
        }
    }
}

// Round 9
// 915.685 us; speedup vs baseline: 1.1501x; 1.1501x over previous
//
#include <hip/hip_runtime.h>

typedef unsigned short UST;
typedef __attribute__((ext_vector_type(8))) __bf16 bf16x8;
typedef __attribute__((ext_vector_type(4))) float f32x4;

__device__ __forceinline__ float bf2f(UST u) {
    union { unsigned int i; float f; } v; v.i = ((unsigned int)u) << 16; return v.f;
}
__device__ __forceinline__ UST f2bf(float f) {
    union { float f; unsigned int i; } v; v.f = f;
    return (UST)((v.i + 0x7fffu + ((v.i >> 16) & 1u)) >> 16);
}

__device__ __forceinline__ void gl2lds16(const UST* g, UST* l) {
    __builtin_amdgcn_global_load_lds(
        (const __attribute__((address_space(1))) unsigned int*)g,
        (__attribute__((address_space(3))) unsigned int*)l, 16, 0, 0);
}

#define LGB asm volatile("s_waitcnt lgkmcnt(0)\n\ts_barrier" ::: "memory")
// rule 18: lgkm wait + sched_barrier so reg-only MFMA can't hoist past it
#define LGW do { asm volatile("s_waitcnt lgkmcnt(0)" ::: "memory"); \
                 __builtin_amdgcn_sched_barrier(0); } while (0)
#define BARR __builtin_amdgcn_s_barrier()
#define EW2 asm volatile("s_waitcnt vmcnt(2)" ::: "memory")
#define EW0 asm volatile("s_waitcnt vmcnt(0)" ::: "memory")
#define EWN do {} while (0)

// ---------------------------------------------------------------------------
// Weight prep v3 (unchanged): W'[o,i] = (qw/15*2-1)*scale + (lb@la)[o,i].
// ---------------------------------------------------------------------------
__global__ __launch_bounds__(256) void prep_w(
    const int* __restrict__ qw, const float* __restrict__ scale,
    const float* __restrict__ la, const float* __restrict__ lb,
    UST* __restrict__ wp)
{
    int l = blockIdx.x, ot = blockIdx.y, it = blockIdx.z;   // 18 x 8 x 8
    __shared__ float buf[8192];
    __shared__ float sc_s[128 * 8];
    int t = threadIdx.x;
    int wave = t >> 6, lane = t & 63;
    int wm = wave >> 1, wn = wave & 1;
    int la15 = lane & 15, qa = lane >> 4;

    {
        int e = t * 4;
        int o = e >> 3, g = e & 7;
        const float* sb = scale + ((size_t)l * 1024 + ot * 128 + o) * 64 + it * 8 + g;
        *(float4*)&sc_s[e] = *(const float4*)sb;
    }

    float* last = buf;
    {
        const float* laB = la + (size_t)l * 32 * 1024 + it * 128;
        #pragma unroll
        for (int p = 0; p < 4; p++) {
            int e = t * 4 + p * 1024;
            int r = e >> 7, i0 = e & 127;
            float4 v = *(const float4*)(laB + (size_t)r * 1024 + i0);
            last[(i0 + 0) * 33 + r] = v.x;
            last[(i0 + 1) * 33 + r] = v.y;
            last[(i0 + 2) * 33 + r] = v.z;
            last[(i0 + 3) * 33 + r] = v.w;
        }
    }

    bf16x8 af[4];
    const float* lbL = lb + ((size_t)l * 1024 + ot * 128 + wm * 64 + la15) * 32 + qa * 8;
    #pragma unroll
    for (int mi = 0; mi < 4; mi++) {
        float4 u0 = *(const float4*)(lbL + mi * 16 * 32);
        float4 u1 = *(const float4*)(lbL + mi * 16 * 32 + 4);
        union { bf16x8 v; UST u[8]; } A;
        A.u[0] = f2bf(u0.x); A.u[1] = f2bf(u0.y); A.u[2] = f2bf(u0.z); A.u[3] = f2bf(u0.w);
        A.u[4] = f2bf(u1.x); A.u[5] = f2bf(u1.y); A.u[6] = f2bf(u1.z); A.u[7] = f2bf(u1.w);
        af[mi] = A.v;
    }

    __syncthreads();

    bf16x8 bfr[4];
    #pragma unroll
    for (int ni = 0; ni < 4; ni++) {
        int iloc = wn * 64 + ni * 16 + la15;
        const float* pp = &last[iloc * 33 + qa * 8];
        union { bf16x8 v; UST u[8]; } B;
        #pragma unroll
        for (int j = 0; j < 8; j++) B.u[j] = f2bf(pp[j]);
        bfr[ni] = B.v;
    }

    f32x4 acc[4][4];
    #pragma unroll
    for (int mi = 0; mi < 4; mi++)
        #pragma unroll
        for (int ni = 0; ni < 4; ni++) {
            acc[mi][ni] = (f32x4){0.f, 0.f, 0.f, 0.f};
            acc[mi][ni] = __builtin_amdgcn_mfma_f32_16x16x32_bf16(
                af[mi], bfr[ni], acc[mi][ni], 0, 0, 0);
        }

    __syncthreads();

    float* cs = buf;
    int cc = t & 15, rw = t >> 4;
    UST* wL = wp + (size_t)l * 1048576;
    const int* qL = qw + (size_t)l * 1048576;
    #pragma unroll
    for (int h = 0; h < 2; ++h) {
        int4 qd[4][2];
        #pragma unroll
        for (int g = 0; g < 4; g++) {
            int rl = g * 16 + rw;
            const int* qrow = qL + (size_t)(ot * 128 + h * 64 + rl) * 1024
                              + it * 128 + cc * 8;
            qd[g][0] = *(const int4*)qrow;
            qd[g][1] = *(const int4*)(qrow + 4);
        }
        if (wm == h) {
            #pragma unroll
            for (int mi = 0; mi < 4; mi++)
                #pragma unroll
                for (int ni = 0; ni < 4; ni++) {
                    int colx = (wn * 64 + ni * 16 + la15) ^ (qa << 4);
                    #pragma unroll
                    for (int r2 = 0; r2 < 4; r2++) {
                        int rl = mi * 16 + qa * 4 + r2;
                        cs[rl * 128 + colx] = acc[mi][ni][r2];
                    }
                }
        }
        LGB;
        #pragma unroll
        for (int g = 0; g < 4; ++g) {
            int rl = g * 16 + rw;
            int swz = ((rl >> 2) & 3) << 2;
            int gr0 = ((cc * 2) ^ swz) * 4;
            float4 v0 = *(const float4*)&cs[rl * 128 + gr0];
            float4 v1 = *(const float4*)&cs[rl * 128 + gr0 + 4];
            float s = sc_s[(h * 64 + rl) * 8 + (cc >> 1)];
            float t2 = s * (2.0f / 15.0f);
            float o0 = fmaf((float)qd[g][0].x, t2, v0.x - s);
            float o1 = fmaf((float)qd[g][0].y, t2, v0.y - s);
            float o2 = fmaf((float)qd[g][0].z, t2, v0.z - s);
            float o3 = fmaf((float)qd[g][0].w, t2, v0.w - s);
            float o4 = fmaf((float)qd[g][1].x, t2, v1.x - s);
            float o5 = fmaf((float)qd[g][1].y, t2, v1.y - s);
            float o6 = fmaf((float)qd[g][1].z, t2, v1.z - s);
            float o7 = fmaf((float)qd[g][1].w, t2, v1.w - s);
            uint4 pk;
            pk.x = (unsigned)f2bf(o0) | ((unsigned)f2bf(o1) << 16);
            pk.y = (unsigned)f2bf(o2) | ((unsigned)f2bf(o3) << 16);
            pk.z = (unsigned)f2bf(o4) | ((unsigned)f2bf(o5) << 16);
            pk.w = (unsigned)f2bf(o6) | ((unsigned)f2bf(o7) << 16);
            *(uint4*)&wL[(size_t)(ot * 128 + h * 64 + rl) * 1024 + it * 128 + cc * 8] = pk;
        }
        LGB;
    }
}

__global__ __launch_bounds__(256) void f32_to_bf16(const float* __restrict__ x,
                                                   UST* __restrict__ o)
{
    size_t i = ((size_t)blockIdx.x * 256 + threadIdx.x) * 4;
    float4 v = *(const float4*)(x + i);
    *(ushort4*)(o + i) = make_ushort4(f2bf(v.x), f2bf(v.y), f2bf(v.z), f2bf(v.w));
}

// ---------------------------------------------------------------------------
// GEMM v9b: m201 8-phase port, ACC-INDEX FIXED (m225 recipe: kk=1 phases
// accumulate into the SAME quadrant accumulators as kk=0 -- R8 wrongly
// indexed acc by K-subtile, overrunning acc[8][4]).
// 256x256 tile, 512 thr, 2Mx4N waves, acc[8][4]. K-tile=64; 16 tiles;
// LDS = 2 slots x {A0,A1,B0,B1 x 16KB} = 128KB. Per K-tile 4 phases:
// {ds_reads ; stage ONE half-tile ; barrier ; lgkm0 ; 16 MFMA ; barrier}.
// Stage: ph0->B1(t+1), ph1->A0(t+1), ph2->A1(t+1), ph3->B0(t+2);
// vmcnt(2) once per K-tile.
// ---------------------------------------------------------------------------
#define BKT 64

__global__ __launch_bounds__(512, 2) void gemm_ep(
    const UST* __restrict__ X, const UST* __restrict__ W,
    const float* __restrict__ bias,
    UST* __restrict__ outb, const UST* __restrict__ resid,
    float* __restrict__ outf, int mode)
{
    const int K = 1024;
    __shared__ UST smem[65536];   // 2 slots x 64KB = 128 KB
    int tid = threadIdx.x;
    int wave = tid >> 6, lane = tid & 63;
    int wm = wave >> 2, wn = wave & 3;         // 2M x 4N waves
    int la15 = lane & 15, qa = lane >> 4;

    int bid = blockIdx.x;
    int xcd = bid & 7, idx = bid >> 3;         // 256 blocks
    int bm = xcd * 8 + (idx & 7);              // 0..63
    int bn = idx >> 3;                         // 0..3

    const UST* srcA[2];
    const UST* srcB[2];
    int dstc[2];
    #pragma unroll
    for (int j = 0; j < 2; j++) {
        int c = tid + j * 512;
        int row = c >> 3, sl = c & 7;
        int kof = (sl ^ (row & 7)) * 8;
        srcA[j] = X + (size_t)(bm * 256 + row) * K + kof;
        srcB[j] = W + (size_t)(bn * 256 + row) * K + kof;
        dstc[j] = c * 8;
    }

    int offA[2][4], offB[2][4];
    #pragma unroll
    for (int kk = 0; kk < 2; kk++) {
        #pragma unroll
        for (int i = 0; i < 4; i++) {
            int rih = i * 16 + la15;                       // rows 0..63 (q=0)
            offA[kk][i] = wm * 8192 + rih * 64 + (((kk * 4 + qa) ^ (rih & 7)) * 8);
            int cih = (wn & 1) * 64 + i * 16 + la15;       // col in B-half
            offB[kk][i] = 16384 + (wn >> 1) * 8192 + cih * 64
                          + (((kk * 4 + qa) ^ (cih & 7)) * 8);
        }
    }

    f32x4 acc[8][4];
    #pragma unroll
    for (int i = 0; i < 8; i++)
        #pragma unroll
        for (int j = 0; j < 4; j++) acc[i][j] = (f32x4){0.f, 0.f, 0.f, 0.f};

    // half id H: 0=A0, 1=A1, 2=B0, 3=B1
    auto stageH = [&](int t, int H) {
        UST* dst = smem + ((t & 1) * 32768 + H * 8192);
        #pragma unroll
        for (int j = 0; j < 2; j++) {
            const UST* src = (H < 2 ? srcA[j] : srcB[j])
                             + (size_t)(H & 1) * (128 * 1024) + t * BKT;
            gl2lds16(src, dst + dstc[j]);
        }
    };

// Q is the OUTPUT quadrant (row half) only -- both kk sub-tiles of the
// K-tile accumulate into the same acc[Q*4+m][n].
#define MF16(Q)                                                             \
    _Pragma("unroll")                                                       \
    for (int m = 0; m < 4; m++)                                             \
        _Pragma("unroll")                                                   \
        for (int n = 0; n < 4; n++)                                         \
            acc[(Q) * 4 + m][n] = __builtin_amdgcn_mfma_f32_16x16x32_bf16(  \
                af[m], bfr[n], acc[(Q) * 4 + m][n], 0, 0, 0)

#define GROUP(T, SP, SN, EW)                                                \
    {                                                                       \
        const UST* p = smem + ((T) & 1) * 32768;                            \
        bf16x8 af[4], bfr[4];                                               \
        /* ph0: Q0 x kk0 */                                                 \
        _Pragma("unroll")                                                   \
        for (int i = 0; i < 4; i++) bfr[i] = *(const bf16x8*)&p[offB[0][i]];\
        _Pragma("unroll")                                                   \
        for (int i = 0; i < 4; i++) af[i] = *(const bf16x8*)&p[offA[0][i]]; \
        if (SP) stageH((T) + 1, 3);                                         \
        BARR; LGW;                                                          \
        __builtin_amdgcn_s_setprio(1); MF16(0); __builtin_amdgcn_s_setprio(0); \
        BARR;                                                               \
        /* ph1: Q1 x kk0 */                                                 \
        _Pragma("unroll")                                                   \
        for (int i = 0; i < 4; i++)                                         \
            af[i] = *(const bf16x8*)&p[offA[0][i] + 4096];                  \
        if (SP) stageH((T) + 1, 0);                                         \
        BARR; LGW;                                                          \
        __builtin_amdgcn_s_setprio(1); MF16(1); __builtin_amdgcn_s_setprio(0); \
        BARR;                                                               \
        /* ph2: Q0 x kk1 -- accumulates into Q0 accs */                     \
        _Pragma("unroll")                                                   \
        for (int i = 0; i < 4; i++) bfr[i] = *(const bf16x8*)&p[offB[1][i]];\
        _Pragma("unroll")                                                   \
        for (int i = 0; i < 4; i++) af[i] = *(const bf16x8*)&p[offA[1][i]]; \
        if (SP) stageH((T) + 1, 1);                                         \
        BARR; LGW;                                                          \
        __builtin_amdgcn_s_setprio(1); MF16(0); __builtin_amdgcn_s_setprio(0); \
        BARR;                                                               \
        /* ph3: Q1 x kk1 -- accumulates into Q1 accs */                     \
        _Pragma("unroll")                                                   \
        for (int i = 0; i < 4; i++)                                         \
            af[i] = *(const bf16x8*)&p[offA[1][i] + 4096];                  \
        if (SN) stageH((T) + 2, 2);                                         \
        BARR; LGW;                                                          \
        __builtin_amdgcn_s_setprio(1); MF16(1); __builtin_amdgcn_s_setprio(0); \
        EW;                                                                 \
        BARR;                                                               \
    }

    // prologue: K-tiles 0 and 1 fully staged; vmcnt(8) => tile 0 landed
    #pragma unroll
    for (int H = 0; H < 4; H++) stageH(0, H);
    #pragma unroll
    for (int H = 0; H < 4; H++) stageH(1, H);
    asm volatile("s_waitcnt vmcnt(8)" ::: "memory");
    BARR;

    GROUP(0, 0, 1, EW2);
    for (int g = 1; g <= 13; ++g) GROUP(g, 1, 1, EW2);
    GROUP(14, 1, 0, EW0);
    GROUP(15, 0, 0, EWN);
#undef GROUP
#undef MF16

    // -------- epilogue: 4 strips of 64x256 fp32 (R4's verified code) -------
    float* cs = (float*)smem;
    int cc = tid & 31, rw = tid >> 5;
    int gcolb = bn * 256 + cc * 8;
    float4 bv0 = *(const float4*)&bias[gcolb];
    float4 bv1 = *(const float4*)&bias[gcolb + 4];

    #pragma unroll
    for (int h = 0; h < 4; ++h) {
        if (wm == (h >> 1)) {
            #pragma unroll
            for (int m = 0; m < 4; m++) {
                int mi = (h & 1) * 4 + m;
                #pragma unroll
                for (int ni = 0; ni < 4; ni++) {
                    int colx = (wn * 64 + ni * 16 + la15) ^ (qa << 4);
                    #pragma unroll
                    for (int r2 = 0; r2 < 4; r2++) {
                        int rl = m * 16 + qa * 4 + r2;
                        cs[rl * 256 + colx] = acc[mi][ni][r2];
                    }
                }
            }
        }
        LGB;
        #pragma unroll
        for (int g = 0; g < 4; ++g) {
            int rl = g * 16 + rw;
            int swz = ((rl >> 2) & 3) << 2;
            int gr0 = ((cc * 2) ^ swz) * 4;
            float4 v0 = *(const float4*)&cs[rl * 256 + gr0];
            float4 v1 = *(const float4*)&cs[rl * 256 + gr0 + 4];
            float o0 = v0.x + bv0.x, o1 = v0.y + bv0.y;
            float o2 = v0.z + bv0.z, o3 = v0.w + bv0.w;
            float o4 = v1.x + bv1.x, o5 = v1.y + bv1.y;
            float o6 = v1.z + bv1.z, o7 = v1.w + bv1.w;
            if (mode == 0) {
                o0 = fmaxf(o0, 0.f); o1 = fmaxf(o1, 0.f);
                o2 = fmaxf(o2, 0.f); o3 = fmaxf(o3, 0.f);
                o4 = fmaxf(o4, 0.f); o5 = fmaxf(o5, 0.f);
                o6 = fmaxf(o6, 0.f); o7 = fmaxf(o7, 0.f);
            }
            int grow = bm * 256 + h * 64 + rl;
            size_t base = (size_t)grow * 1024 + gcolb;
            if (mode != 0) {
                ushort4 rv0 = *(const ushort4*)&resid[base];
                ushort4 rv1 = *(const ushort4*)&resid[base + 4];
                o0 += bf2f(rv0.x); o1 += bf2f(rv0.y);
                o2 += bf2f(rv0.z); o3 += bf2f(rv0.w);
                o4 += bf2f(rv1.x); o5 += bf2f(rv1.y);
                o6 += bf2f(rv1.z); o7 += bf2f(rv1.w);
            }
            if (mode == 2) {
                *(float4*)&outf[base] = make_float4(o0, o1, o2, o3);
                *(float4*)&outf[base + 4] = make_float4(o4, o5, o6, o7);
            } else {
                uint4 pk;
                pk.x = (unsigned)f2bf(o0) | ((unsigned)f2bf(o1) << 16);
                pk.y = (unsigned)f2bf(o2) | ((unsigned)f2bf(o3) << 16);
                pk.z = (unsigned)f2bf(o4) | ((unsigned)f2bf(o5) << 16);
                pk.w = (unsigned)f2bf(o6) | ((unsigned)f2bf(o7) << 16);
                *(uint4*)&outb[base] = pk;
            }
        }
        LGB;
    }
}

// ---------------------------------------------------------------------------
// Slim LayerNorm (unchanged).
// ---------------------------------------------------------------------------
__global__ __launch_bounds__(256) void ln_only(
    const UST* __restrict__ s, UST* __restrict__ r,
    const float* __restrict__ g, const float* __restrict__ b)
{
    int wave = threadIdx.x >> 6, lane = threadIdx.x & 63;
    int row = blockIdx.x * 4 + wave;
    const UST* sp = s + (size_t)row * 1024;
    UST* rp = r + (size_t)row * 1024;

    float v[16];
    float sum = 0.f, ss = 0.f;
    #pragma unroll
    for (int k = 0; k < 4; k++) {
        ushort4 hv = *(const ushort4*)(sp + k * 256 + lane * 4);
        float a0 = bf2f(hv.x), a1 = bf2f(hv.y), a2 = bf2f(hv.z), a3 = bf2f(hv.w);
        v[k * 4 + 0] = a0; v[k * 4 + 1] = a1; v[k * 4 + 2] = a2; v[k * 4 + 3] = a3;
        sum += a0 + a1 + a2 + a3;
        ss += a0 * a0 + a1 * a1 + a2 * a2 + a3 * a3;
    }
    #pragma unroll
    for (int off = 32; off > 0; off >>= 1) {
        sum += __shfl_down(sum, off, 64);
        ss  += __shfl_down(ss, off, 64);
    }
    sum = __shfl(sum, 0, 64);
    ss  = __shfl(ss, 0, 64);
    float mean = sum * (1.0f / 1024.0f);
    float var = ss * (1.0f / 1024.0f) - mean * mean;
    float rstd = rsqrtf(var + 1e-5f);

    #pragma unroll
    for (int k = 0; k < 4; k++) {
        int c = k * 256 + lane * 4;
        float4 gv = *(const float4*)(g + c);
        float4 bv = *(const float4*)(b + c);
        ushort4 o;
        o.x = f2bf((v[k * 4 + 0] - mean) * rstd * gv.x + bv.x);
        o.y = f2bf((v[k * 4 + 1] - mean) * rstd * gv.y + bv.y);
        o.z = f2bf((v[k * 4 + 2] - mean) * rstd * gv.z + bv.z);
        o.w = f2bf((v[k * 4 + 3] - mean) * rstd * gv.w + bv.w);
        *(ushort4*)(rp + c) = o;
    }
}

// ---------------------------------------------------------------------------
extern "C" void kernel_launch(void* const* d_in, const int* in_sizes, int n_in,
                              void* d_out, int out_size, void* d_ws, size_t ws_size,
                              hipStream_t stream) {
    const float* x     = (const float*)d_in[0];
    const float* scale = (const float*)d_in[1];
    const float* bias  = (const float*)d_in[2];
    const float* la    = (const float*)d_in[3];
    const float* lb    = (const float*)d_in[4];
    const float* ln_w  = (const float*)d_in[5];
    const float* ln_b  = (const float*)d_in[6];
    const int*   qw    = (const int*)d_in[7];

    const int M = in_sizes[0] / 1024;                  // 16384
    const size_t WPB = (size_t)18 * 1024 * 1024 * 2;
    const size_t ACT = (size_t)M * 1024 * 2;

    UST* wp = (UST*)d_ws;
    UST* A  = (UST*)((char*)d_ws + WPB);            // residual
    UST* Cb = (UST*)((char*)d_ws + WPB + ACT);      // ping
    UST* Bb = (UST*)d_out;                          // pong (dead before fp32 write)

    prep_w<<<dim3(18, 8, 8), 256, 0, stream>>>(qw, scale, la, lb, wp);
    f32_to_bf16<<<(M * 1024) / (256 * 4), 256, 0, stream>>>(x, A);

    int nblk = (M / 256) * 4;                          // 256 blocks = 1/CU
    int li = 0;
    for (int blk = 0; blk < 6; ++blk) {
        gemm_ep<<<nblk, 512, 0, stream>>>(
            A, wp + (size_t)li * 1024 * 1024, bias + li * 1024, Bb, nullptr, nullptr, 0);
        li++;
        gemm_ep<<<nblk, 512, 0, stream>>>(
            Bb, wp + (size_t)li * 1024 * 1024, bias + li * 1024, Cb, nullptr, nullptr, 0);
        li++;
        if (blk < 5) {
            gemm_ep<<<nblk, 512, 0, stream>>>(
                Cb, wp + (size_t)li * 1024 * 1024, bias + li * 1024, Bb, A, nullptr, 1);
            li++;
            ln_only<<<M / 4, 256, 0, stream>>>(Bb, A, ln_w + blk * 1024, ln_b + blk * 1024);
        } else {
            gemm_ep<<<nblk, 512, 0, stream>>>(
                Cb, wp + (size_t)li * 1024 * 1024, bias + li * 1024, nullptr, A,
                (float*)d_out, 2);
            li++;
        }
    }
}